// Round 1
// baseline (467.297 us; speedup 1.0000x reference)
//
#include <hip/hip_runtime.h>

typedef float  f32x4  __attribute__((ext_vector_type(4)));
typedef __bf16 bf16x8 __attribute__((ext_vector_type(8)));

#define N_NODES 16384
#define K_DIM   16384
#define H1_DIM  50
#define H1_PAD  64
#define OUT_OFF (N_NODES * 7)

// ---------------- init: zero xw, deg = 1 (self loop) ----------------
__global__ __launch_bounds__(256) void k_init(float* xw, int* deg) {
  int i = blockIdx.x * 256 + threadIdx.x;
  if (i < N_NODES * H1_PAD) xw[i] = 0.f;
  if (i < N_NODES) deg[i] = 1;
}

// ---------------- degree count over dst ----------------
__global__ __launch_bounds__(256) void k_count(const int* __restrict__ dst, int E, int* deg) {
  int e = blockIdx.x * 256 + threadIdx.x;
  if (e < E) atomicAdd(&deg[dst[e]], 1);
}

// ---------------- single-block scan: dinv, CSR row_ptr, cursor ----------------
__global__ __launch_bounds__(1024) void k_scan(const int* __restrict__ deg, float* dinv,
                                               int* row_ptr, int* cursor) {
  __shared__ int part[1024];
  int t = threadIdx.x;
  int base = t * 16;
  int loc[16];
  int s = 0;
#pragma unroll
  for (int i = 0; i < 16; ++i) {
    int d = deg[base + i];
    dinv[base + i] = rsqrtf((float)d);
    loc[i] = s;
    s += d - 1;  // incoming edge count (excl self loop)
  }
  part[t] = s;
  __syncthreads();
  for (int off = 1; off < 1024; off <<= 1) {
    int v = (t >= off) ? part[t - off] : 0;
    __syncthreads();
    part[t] += v;
    __syncthreads();
  }
  int excl = (t > 0) ? part[t - 1] : 0;
#pragma unroll
  for (int i = 0; i < 16; ++i) {
    int rp = excl + loc[i];
    row_ptr[base + i] = rp;
    cursor[base + i] = rp;
  }
  if (t == 1023) row_ptr[N_NODES] = excl + s;
}

// ---------------- W1 -> WT (bf16, transposed [64][16384], cols 50..63 zero) ----------------
__global__ __launch_bounds__(256) void k_wt(const float* __restrict__ W1, __bf16* __restrict__ WT) {
  __shared__ __bf16 lds[64][80];
  int t = threadIdx.x;
  int k0 = blockIdx.x * 64;
  int rq = t >> 6, c = t & 63;
  for (int r = 0; r < 16; ++r) {
    int row = rq * 16 + r;
    __bf16 v = (__bf16)0.f;
    if (c < H1_DIM) v = (__bf16)W1[(size_t)(k0 + row) * H1_DIM + c];
    lds[c][row] = v;
  }
  __syncthreads();
  int cw = t >> 2, kq = (t & 3) * 16;
  __bf16* dp = WT + (size_t)cw * K_DIM + k0 + kq;
  *(bf16x8*)dp       = *(const bf16x8*)&lds[cw][kq];
  *((bf16x8*)dp + 1) = *(const bf16x8*)&lds[cw][kq + 8];
}

// ---------------- CSR fill ----------------
__global__ __launch_bounds__(256) void k_fill(const int* __restrict__ src, const int* __restrict__ dst,
                                              int E, int* cursor, int* csr_src) {
  int e = blockIdx.x * 256 + threadIdx.x;
  if (e < E) {
    int pos = atomicAdd(&cursor[dst[e]], 1);
    csr_src[pos] = src[e];
  }
}

// ---------------- GEMM1: xw[r][c] += dinv[r] * (x @ W1)[r][c]  (bf16 MFMA, split-K=4) ----------------
__global__ __launch_bounds__(256) void k_gemm1(const float* __restrict__ x,
                                               const __bf16* __restrict__ WT,
                                               const float* __restrict__ dinv,
                                               float* __restrict__ xw) {
  int tid = threadIdx.x;
  int w = tid >> 6, l = tid & 63;
  int l15 = l & 15, lk = (l >> 4) * 8;
  int arow = blockIdx.x * 64 + w * 16 + l15;
  int kbase = blockIdx.y * 4096;

  const float*  ap  = x  + (size_t)arow * K_DIM + kbase + lk;
  const __bf16* bp0 = WT + (size_t)(l15)      * K_DIM + kbase + lk;
  const __bf16* bp1 = WT + (size_t)(16 + l15) * K_DIM + kbase + lk;
  const __bf16* bp2 = WT + (size_t)(32 + l15) * K_DIM + kbase + lk;
  const __bf16* bp3 = WT + (size_t)(48 + l15) * K_DIM + kbase + lk;

  f32x4 acc0 = {0, 0, 0, 0}, acc1 = {0, 0, 0, 0}, acc2 = {0, 0, 0, 0}, acc3 = {0, 0, 0, 0};

#pragma unroll 2
  for (int kk = 0; kk < 4096; kk += 32) {
    f32x4 a0 = *(const f32x4*)(ap + kk);
    f32x4 a1 = *(const f32x4*)(ap + kk + 4);
    bf16x8 af;
    af[0] = (__bf16)a0[0]; af[1] = (__bf16)a0[1]; af[2] = (__bf16)a0[2]; af[3] = (__bf16)a0[3];
    af[4] = (__bf16)a1[0]; af[5] = (__bf16)a1[1]; af[6] = (__bf16)a1[2]; af[7] = (__bf16)a1[3];
    bf16x8 b0 = *(const bf16x8*)(bp0 + kk);
    bf16x8 b1 = *(const bf16x8*)(bp1 + kk);
    bf16x8 b2 = *(const bf16x8*)(bp2 + kk);
    bf16x8 b3 = *(const bf16x8*)(bp3 + kk);
    acc0 = __builtin_amdgcn_mfma_f32_16x16x32_bf16(af, b0, acc0, 0, 0, 0);
    acc1 = __builtin_amdgcn_mfma_f32_16x16x32_bf16(af, b1, acc1, 0, 0, 0);
    acc2 = __builtin_amdgcn_mfma_f32_16x16x32_bf16(af, b2, acc2, 0, 0, 0);
    acc3 = __builtin_amdgcn_mfma_f32_16x16x32_bf16(af, b3, acc3, 0, 0, 0);
  }

  // C layout (verified): col = lane&15, row = (lane>>4)*4 + reg
  int crow = blockIdx.x * 64 + w * 16 + (l >> 4) * 4;
#pragma unroll
  for (int j = 0; j < 4; ++j) {
    float dv = dinv[crow + j];
    size_t rb = (size_t)(crow + j) * H1_PAD + l15;
    atomicAdd(&xw[rb],      acc0[j] * dv);
    atomicAdd(&xw[rb + 16], acc1[j] * dv);
    atomicAdd(&xw[rb + 32], acc2[j] * dv);
    atomicAdd(&xw[rb + 48], acc3[j] * dv);
  }
}

// ---------------- layer-1 aggregation: h1 = tanh(dinv[i]*(sum_src xw_s + xw_i) + b1) ----------------
__global__ __launch_bounds__(256) void k_agg1(const float* __restrict__ xw,
                                              const int* __restrict__ row_ptr,
                                              const int* __restrict__ csr_src,
                                              const float* __restrict__ dinv,
                                              const float* __restrict__ b1,
                                              float* __restrict__ h1) {
  int tid = threadIdx.x;
  int nid = blockIdx.x * 4 + (tid >> 6);
  int j = tid & 63;
  float acc = xw[(size_t)nid * H1_PAD + j];  // self term (already dinv[src]-scaled)
  int s = row_ptr[nid], e = row_ptr[nid + 1];
  int p = s;
  for (; p + 3 < e; p += 4) {
    int s0 = csr_src[p], s1 = csr_src[p + 1], s2 = csr_src[p + 2], s3 = csr_src[p + 3];
    acc += xw[(size_t)s0 * H1_PAD + j];
    acc += xw[(size_t)s1 * H1_PAD + j];
    acc += xw[(size_t)s2 * H1_PAD + j];
    acc += xw[(size_t)s3 * H1_PAD + j];
  }
  for (; p < e; ++p) acc += xw[(size_t)csr_src[p] * H1_PAD + j];
  float bj = (j < H1_DIM) ? b1[j] : 0.f;
  h1[(size_t)nid * H1_PAD + j] = tanhf(dinv[nid] * acc + bj);
}

// ---------------- layer-2 transform: xw2s[i] = dinv[i] * (h1[i] @ W2) ----------------
__global__ __launch_bounds__(256) void k_xw2(const float* __restrict__ h1,
                                             const float* __restrict__ W2,
                                             const float* __restrict__ dinv,
                                             float* __restrict__ xw2s) {
  __shared__ float w2[100];
  int tid = threadIdx.x;
  if (tid < 100) w2[tid] = W2[tid];
  __syncthreads();
  int i = blockIdx.x * 256 + tid;
  float a0 = 0.f, a1 = 0.f;
#pragma unroll
  for (int jj = 0; jj < H1_DIM; ++jj) {
    float v = h1[(size_t)i * H1_PAD + jj];
    a0 += v * w2[jj * 2];
    a1 += v * w2[jj * 2 + 1];
  }
  float dv = dinv[i];
  xw2s[i * 2]     = a0 * dv;
  xw2s[i * 2 + 1] = a1 * dv;
}

// ---------------- layer-2 aggregation + tanh + classifier ----------------
__global__ __launch_bounds__(256) void k_final(const float* __restrict__ xw2s,
                                               const int* __restrict__ row_ptr,
                                               const int* __restrict__ csr_src,
                                               const float* __restrict__ dinv,
                                               const float* __restrict__ b2,
                                               const float* __restrict__ Wc,
                                               const float* __restrict__ bc,
                                               float* __restrict__ dout) {
  int tid = threadIdx.x;
  int g = tid >> 4, r = tid & 15;
  int nid = blockIdx.x * 16 + g;
  int s = row_ptr[nid], e = row_ptr[nid + 1];
  float a0 = 0.f, a1 = 0.f;
  for (int p = s + r; p < e; p += 16) {
    int sc = csr_src[p];
    a0 += xw2s[sc * 2];
    a1 += xw2s[sc * 2 + 1];
  }
#pragma unroll
  for (int off = 8; off >= 1; off >>= 1) {
    a0 += __shfl_xor(a0, off, 16);
    a1 += __shfl_xor(a1, off, 16);
  }
  if (r == 0) {
    a0 += xw2s[nid * 2];
    a1 += xw2s[nid * 2 + 1];
    float dv = dinv[nid];
    float h0  = tanhf(dv * a0 + b2[0]);
    float h1v = tanhf(dv * a1 + b2[1]);
#pragma unroll
    for (int j = 0; j < 7; ++j)
      dout[nid * 7 + j] = h0 * Wc[j] + h1v * Wc[7 + j] + bc[j];
    dout[OUT_OFF + nid * 2]     = h0;
    dout[OUT_OFF + nid * 2 + 1] = h1v;
  }
}

extern "C" void kernel_launch(void* const* d_in, const int* in_sizes, int n_in,
                              void* d_out, int out_size, void* d_ws, size_t ws_size,
                              hipStream_t stream) {
  const float* x  = (const float*)d_in[0];
  const int*   ei = (const int*)d_in[1];
  const float* W1 = (const float*)d_in[2];
  const float* b1 = (const float*)d_in[3];
  const float* W2 = (const float*)d_in[4];
  const float* b2 = (const float*)d_in[5];
  const float* Wc = (const float*)d_in[6];
  const float* bc = (const float*)d_in[7];
  float* dout = (float*)d_out;
  const int E = in_sizes[1] / 2;
  const int* esrc = ei;
  const int* edst = ei + E;

  char* ws = (char*)d_ws;
  float*  xw      = (float*)(ws + 0x000000);   // 4 MiB  [16384][64]
  float*  h1      = (float*)(ws + 0x400000);   // 4 MiB  [16384][64]
  __bf16* WT      = (__bf16*)(ws + 0x800000);  // 2 MiB  [64][16384]
  int*    deg     = (int*)(ws + 0xA00000);     // 64 KiB
  float*  dinv    = (float*)(ws + 0xA10000);   // 64 KiB
  int*    row_ptr = (int*)(ws + 0xA20000);     // 64 KiB + 4
  int*    cursor  = (int*)(ws + 0xA40000);     // 64 KiB
  int*    csr     = (int*)(ws + 0xA50000);     // 2 MiB
  float*  xw2s    = (float*)(ws + 0xC50000);   // 128 KiB

  k_init<<<(N_NODES * H1_PAD + 255) / 256, 256, 0, stream>>>(xw, deg);
  k_count<<<(E + 255) / 256, 256, 0, stream>>>(edst, E, deg);
  k_scan<<<1, 1024, 0, stream>>>(deg, dinv, row_ptr, cursor);
  k_wt<<<K_DIM / 64, 256, 0, stream>>>(W1, WT);
  k_fill<<<(E + 255) / 256, 256, 0, stream>>>(esrc, edst, E, cursor, csr);
  k_gemm1<<<dim3(256, 4), 256, 0, stream>>>(x, WT, dinv, xw);
  k_agg1<<<N_NODES / 4, 256, 0, stream>>>(xw, row_ptr, csr, dinv, b1, h1);
  k_xw2<<<N_NODES / 256, 256, 0, stream>>>(h1, W2, dinv, xw2s);
  k_final<<<N_NODES / 16, 256, 0, stream>>>(xw2s, row_ptr, csr, dinv, b2, Wc, bc, dout);
}